// Round 1
// baseline (8223.588 us; speedup 1.0000x reference)
//
#include <hip/hip_runtime.h>
#include <stdint.h>

#define B_N 16
#define S_N 256
#define H_N 512
#define V_N 32000
#define G4_N 2048
#define START_TOK 1

typedef float f32x4 __attribute__((ext_vector_type(4)));
typedef int   i32x4 __attribute__((ext_vector_type(4)));
typedef unsigned short u16;
typedef u16 u16x4 __attribute__((ext_vector_type(4)));

static __device__ __forceinline__ u16 f2bf(float f) {
  unsigned u = __float_as_uint(f);
  return (u16)((u + 0x7fffu + ((u >> 16) & 1u)) >> 16);  // RNE
}

// MFMA via inline asm: avoids builtin operand-type ambiguity (short8 vs __bf16x8).
// A/B frag: lane holds row=(lane&15), k=(lane>>4)*8 + 0..7 (16B contiguous, K-major).
// D frag:   lane reg r -> row=(lane>>4)*4+r, col=(lane&15).   [m89/m91 verified]
static __device__ __forceinline__ void mfma_bf16_16x16x32(f32x4& d, i32x4 a, i32x4 b) {
  asm("v_mfma_f32_16x16x32_bf16 %0, %1, %2, %0" : "+v"(d) : "v"(a), "v"(b));
}

// async global->LDS, 16B per lane. LDS dest must be wave-uniform; HW adds lane*16.
static __device__ __forceinline__ void async16(const void* g, void* l) {
  __builtin_amdgcn_global_load_lds((const __attribute__((address_space(1))) unsigned*)g,
                                   (__attribute__((address_space(3))) unsigned*)l,
                                   16, 0, 0);
}

// ---------------- prep kernels ----------------

__global__ void cast_bf16_kernel(const float* __restrict__ in, u16* __restrict__ out, int n4) {
  int i = blockIdx.x * blockDim.x + threadIdx.x;
  int stride = gridDim.x * blockDim.x;
  for (int q = i; q < n4; q += stride) {
    f32x4 v = *(const f32x4*)(in + 4l * q);
    u16x4 o;
    o.x = f2bf(v.x); o.y = f2bf(v.y); o.z = f2bf(v.z); o.w = f2bf(v.w);
    *(u16x4*)(out + 4l * q) = o;
  }
}

// Wp[k*512 + u] = {W_hh[u][k], W_hh[u+512][k], W_hh[u+1024][k], W_hh[u+1536][k]}
__global__ void pack_whh_kernel(const float* __restrict__ W, f32x4* __restrict__ out) {
  int idx = blockIdx.x * blockDim.x + threadIdx.x;
  if (idx >= H_N * H_N) return;
  int u = idx & (H_N - 1);
  int k = idx >> 9;
  f32x4 v;
  v.x = W[(u)        * H_N + k];
  v.y = W[(u +  512) * H_N + k];
  v.z = W[(u + 1024) * H_N + k];
  v.w = W[(u + 1536) * H_N + k];
  out[k * H_N + u] = v;
}

// ---------------- bf16 MFMA GEMM: C[M][N] = A[M][K] * Bm[N][K]^T + bias ----------------
// 128x128 tile, BK=32, 256 threads = 4 waves (2x2 of 64x64), m97 structure.
// GATHER: A rows indexed via teacher-forced tokens (emb lookup fused into staging).

template<bool GATHER>
__global__ __launch_bounds__(256)
void gemm_bf16_128(const u16* __restrict__ A, const u16* __restrict__ Bm,
                   float* __restrict__ C, int N,
                   const float* __restrict__ bias0, const float* __restrict__ bias1,
                   const int* __restrict__ target) {
  constexpr int K = H_N;  // 512
  __shared__ u16 Alds[128 * 32];
  __shared__ u16 Blds[128 * 32];
  const int tid  = threadIdx.x;
  const int lane = tid & 63;
  const int wq   = tid >> 6;
  const int mbase = blockIdx.y * 128;
  const int nbase = blockIdx.x * 128;

  // staging map: thread tid covers row r=tid/4 (and r+64), 16B chunk (tid&3)
  const int r     = tid >> 2;
  const int off16 = (tid & 3) << 4;

  long arow0, arow1;
  if (GATHER) {
    int m0 = mbase + r, m1 = mbase + 64 + r;
    int t0 = m0 & (S_N - 1), b0 = m0 >> 8;
    int t1 = m1 & (S_N - 1), b1 = m1 >> 8;
    arow0 = (t0 == 0) ? START_TOK : target[b0 * S_N + t0 - 1];
    arow1 = (t1 == 0) ? START_TOK : target[b1 * S_N + t1 - 1];
  } else {
    arow0 = mbase + r;
    arow1 = mbase + 64 + r;
  }
  const long brow0 = nbase + r, brow1 = nbase + 64 + r;

  char* AldsB = (char*)Alds;
  char* BldsB = (char*)Blds;
  const char* Ab = (const char*)A;
  const char* Bb = (const char*)Bm;
  const int ldsw = wq << 10;  // wave-uniform LDS base (1KB per wave-issue)

  const int wm   = (wq >> 1) << 6;
  const int wn   = (wq & 1) << 6;
  const int lrow = lane & 15;
  const int lk   = (lane >> 4) << 3;

  f32x4 acc[4][4] = {};

  for (int kt = 0; kt < K / 32; ++kt) {
    __syncthreads();
    const long kb = kt * 64 + off16;
    async16(Ab + arow0 * (K * 2) + kb, AldsB + ldsw);
    async16(Ab + arow1 * (K * 2) + kb, AldsB + 4096 + ldsw);
    async16(Bb + brow0 * (K * 2) + kb, BldsB + ldsw);
    async16(Bb + brow1 * (K * 2) + kb, BldsB + 4096 + ldsw);
    __syncthreads();  // drains vmcnt -> LDS tiles ready

    i32x4 a[4], b[4];
    #pragma unroll
    for (int mi = 0; mi < 4; ++mi)
      a[mi] = *(const i32x4*)(AldsB + (((wm + mi * 16 + lrow) << 5) + lk) * 2);
    #pragma unroll
    for (int ni = 0; ni < 4; ++ni)
      b[ni] = *(const i32x4*)(BldsB + (((wn + ni * 16 + lrow) << 5) + lk) * 2);
    #pragma unroll
    for (int mi = 0; mi < 4; ++mi)
      #pragma unroll
      for (int ni = 0; ni < 4; ++ni)
        mfma_bf16_16x16x32(acc[mi][ni], a[mi], b[ni]);
  }
  asm volatile("s_nop 7\n\ts_nop 7");  // MFMA->VALU read hazard insurance

  const int rbase = (lane >> 4) << 2;
  #pragma unroll
  for (int ni = 0; ni < 4; ++ni) {
    const int col = nbase + wn + ni * 16 + lrow;
    float bv = bias0[col];
    if (bias1) bv += bias1[col];
    #pragma unroll
    for (int mi = 0; mi < 4; ++mi) {
      const int row = mbase + wm + mi * 16 + rbase;
      f32x4 v = acc[mi][ni];
      C[(long)(row + 0) * N + col] = v.x + bv;
      C[(long)(row + 1) * N + col] = v.y + bv;
      C[(long)(row + 2) * N + col] = v.z + bv;
      C[(long)(row + 3) * N + col] = v.w + bv;
    }
  }
}

// ---------------- LSTM scan: 1 block per batch element ----------------
// Thread t owns hidden unit t: all 4 gates via packed W, c in register, h in LDS.

__global__ __launch_bounds__(512)
void lstm_scan_kernel(const float* __restrict__ xW, const f32x4* __restrict__ Wp,
                      const float* __restrict__ h0, const float* __restrict__ c0,
                      u16* __restrict__ hs) {
  __shared__ float h_sh[H_N];
  const int b = blockIdx.x;
  const int t = threadIdx.x;
  h_sh[t] = h0[b * H_N + t];
  float c = c0[b * H_N + t];
  __syncthreads();
  const float* xWb = xW + (long)b * S_N * G4_N;
  u16* hsb = hs + (long)b * S_N * H_N;

  for (int step = 0; step < S_N; ++step) {
    const float* xr = xWb + step * G4_N;
    f32x4 acc;
    acc.x = xr[t];
    acc.y = xr[t + 512];
    acc.z = xr[t + 1024];
    acc.w = xr[t + 1536];
    #pragma unroll 2
    for (int k = 0; k < H_N; k += 4) {
      f32x4 h4 = *(const f32x4*)(h_sh + k);   // broadcast ds_read_b128
      acc += h4.x * Wp[(k + 0) * H_N + t];    // coalesced 16B global loads (L2-resident)
      acc += h4.y * Wp[(k + 1) * H_N + t];
      acc += h4.z * Wp[(k + 2) * H_N + t];
      acc += h4.w * Wp[(k + 3) * H_N + t];
    }
    __syncthreads();  // all reads of h_sh done before overwrite
    float ig = 1.f / (1.f + expf(-acc.x));
    float fg = 1.f / (1.f + expf(-acc.y));
    float gg = tanhf(acc.z);
    float og = 1.f / (1.f + expf(-acc.w));
    c = fg * c + ig * gg;
    float h = og * tanhf(c);
    h_sh[t] = h;
    hsb[step * H_N + t] = f2bf(h);
    __syncthreads();  // new h visible for next step
  }
}

// ---------------- launcher ----------------

extern "C" void kernel_launch(void* const* d_in, const int* in_sizes, int n_in,
                              void* d_out, int out_size, void* d_ws, size_t ws_size,
                              hipStream_t stream) {
  const int*   target = (const int*)  d_in[0];
  const float* h0     = (const float*)d_in[1];
  const float* c0     = (const float*)d_in[2];
  const float* emb    = (const float*)d_in[3];
  const float* W_ih   = (const float*)d_in[4];
  // d_in[5] = W_hh
  const float* b_ih   = (const float*)d_in[6];
  const float* b_hh   = (const float*)d_in[7];
  const float* out_b  = (const float*)d_in[8];
  const float* W_hh   = (const float*)d_in[5];
  float* out = (float*)d_out;

  char* ws = (char*)d_ws;
  u16*   E16   = (u16*)  (ws);              // V*H bf16           = 32,768,000 B
  u16*   Wih16 = (u16*)  (ws + 32768000);   // 4H*H bf16          =  2,097,152 B
  f32x4* Wpk   = (f32x4*)(ws + 34865152);   // H*H float4         =  4,194,304 B
  float* xW    = (float*)(ws + 39059456);   // B*S*4H f32         = 33,554,432 B
  u16*   hs16  = (u16*)  (ws + 72613888);   // B*S*H bf16         =  4,194,304 B
  (void)ws_size; (void)in_sizes; (void)n_in; (void)out_size;

  cast_bf16_kernel<<<2048, 256, 0, stream>>>(emb,  E16,   (V_N * H_N) / 4);
  cast_bf16_kernel<<<1024, 256, 0, stream>>>(W_ih, Wih16, (G4_N * H_N) / 4);
  pack_whh_kernel <<<1024, 256, 0, stream>>>(W_hh, Wpk);

  // xW = emb[tokens] @ W_ih^T + (b_ih + b_hh)
  gemm_bf16_128<true><<<dim3(G4_N / 128, (B_N * S_N) / 128), 256, 0, stream>>>(
      E16, Wih16, xW, G4_N, b_ih, b_hh, target);

  lstm_scan_kernel<<<B_N, 512, 0, stream>>>(xW, Wpk, h0, c0, hs16);

  // logits = hs @ E^T + out_bias
  gemm_bf16_128<false><<<dim3(V_N / 128, (B_N * S_N) / 128), 256, 0, stream>>>(
      hs16, E16, out, V_N, out_b, nullptr, nullptr);
}

// Round 3
// 2376.798 us; speedup vs baseline: 3.4599x; 3.4599x over previous
//
#include <hip/hip_runtime.h>
#include <stdint.h>

#define B_N 16
#define S_N 256
#define H_N 512
#define V_N 32000
#define G4_N 2048
#define START_TOK 1
#define NBLK 16   // scan blocks
#define UPB 32    // hidden units per scan block
#define ROWS 128  // gate rows per scan block (4 * UPB)

typedef float f32x4 __attribute__((ext_vector_type(4)));
typedef int   i32x4 __attribute__((ext_vector_type(4)));
typedef unsigned short u16;
typedef u16 u16x4 __attribute__((ext_vector_type(4)));

static __device__ __forceinline__ u16 f2bf(float f) {
  unsigned u = __float_as_uint(f);
  return (u16)((u + 0x7fffu + ((u >> 16) & 1u)) >> 16);  // RNE
}
static __device__ __forceinline__ float bf2f(u16 b) {
  return __uint_as_float(((unsigned)b) << 16);
}

// A/B frag: lane holds row=(lane&15), k=(lane>>4)*8 + 0..7 (16B contiguous).
// D frag:   reg r -> row=(lane>>4)*4+r (A side), col=(lane&15) (B side).
static __device__ __forceinline__ void mfma_bf16_16x16x32(f32x4& d, i32x4 a, i32x4 b) {
  asm("v_mfma_f32_16x16x32_bf16 %0, %1, %2, %0" : "+v"(d) : "v"(a), "v"(b));
}

static __device__ __forceinline__ void async16(const void* g, void* l) {
  __builtin_amdgcn_global_load_lds((const __attribute__((address_space(1))) unsigned*)g,
                                   (__attribute__((address_space(3))) unsigned*)l,
                                   16, 0, 0);
}

// ---------------- prep kernels ----------------

__global__ void cast_bf16_kernel(const float* __restrict__ in, u16* __restrict__ out, int n4) {
  int i = blockIdx.x * blockDim.x + threadIdx.x;
  int stride = gridDim.x * blockDim.x;
  for (int q = i; q < n4; q += stride) {
    f32x4 v = *(const f32x4*)(in + 4l * q);
    u16x4 o;
    o.x = f2bf(v.x); o.y = f2bf(v.y); o.z = f2bf(v.z); o.w = f2bf(v.w);
    *(u16x4*)(out + 4l * q) = o;
  }
}

__global__ void zero_ctr_kernel(unsigned* __restrict__ ctr) {
  ctr[threadIdx.x] = 0u;
}

// ---------------- bf16 MFMA GEMM (round-1 verified, unchanged) ----------------

template<bool GATHER>
__global__ __launch_bounds__(256)
void gemm_bf16_128(const u16* __restrict__ A, const u16* __restrict__ Bm,
                   float* __restrict__ C, int N,
                   const float* __restrict__ bias0, const float* __restrict__ bias1,
                   const int* __restrict__ target) {
  constexpr int K = H_N;  // 512
  __shared__ u16 Alds[128 * 32];
  __shared__ u16 Blds[128 * 32];
  const int tid  = threadIdx.x;
  const int lane = tid & 63;
  const int wq   = tid >> 6;
  const int mbase = blockIdx.y * 128;
  const int nbase = blockIdx.x * 128;

  const int r     = tid >> 2;
  const int off16 = (tid & 3) << 4;

  long arow0, arow1;
  if (GATHER) {
    int m0 = mbase + r, m1 = mbase + 64 + r;
    int t0 = m0 & (S_N - 1), b0 = m0 >> 8;
    int t1 = m1 & (S_N - 1), b1 = m1 >> 8;
    arow0 = (t0 == 0) ? START_TOK : target[b0 * S_N + t0 - 1];
    arow1 = (t1 == 0) ? START_TOK : target[b1 * S_N + t1 - 1];
  } else {
    arow0 = mbase + r;
    arow1 = mbase + 64 + r;
  }
  const long brow0 = nbase + r, brow1 = nbase + 64 + r;

  char* AldsB = (char*)Alds;
  char* BldsB = (char*)Blds;
  const char* Ab = (const char*)A;
  const char* Bb = (const char*)Bm;
  const int ldsw = wq << 10;

  const int wm   = (wq >> 1) << 6;
  const int wn   = (wq & 1) << 6;
  const int lrow = lane & 15;
  const int lk   = (lane >> 4) << 3;

  f32x4 acc[4][4] = {};

  for (int kt = 0; kt < K / 32; ++kt) {
    __syncthreads();
    const long kb = kt * 64 + off16;
    async16(Ab + arow0 * (K * 2) + kb, AldsB + ldsw);
    async16(Ab + arow1 * (K * 2) + kb, AldsB + 4096 + ldsw);
    async16(Bb + brow0 * (K * 2) + kb, BldsB + ldsw);
    async16(Bb + brow1 * (K * 2) + kb, BldsB + 4096 + ldsw);
    __syncthreads();

    i32x4 a[4], b[4];
    #pragma unroll
    for (int mi = 0; mi < 4; ++mi)
      a[mi] = *(const i32x4*)(AldsB + (((wm + mi * 16 + lrow) << 5) + lk) * 2);
    #pragma unroll
    for (int ni = 0; ni < 4; ++ni)
      b[ni] = *(const i32x4*)(BldsB + (((wn + ni * 16 + lrow) << 5) + lk) * 2);
    #pragma unroll
    for (int mi = 0; mi < 4; ++mi)
      #pragma unroll
      for (int ni = 0; ni < 4; ++ni)
        mfma_bf16_16x16x32(acc[mi][ni], a[mi], b[ni]);
  }
  asm volatile("s_nop 7\n\ts_nop 7");

  const int rbase = (lane >> 4) << 2;
  #pragma unroll
  for (int ni = 0; ni < 4; ++ni) {
    const int col = nbase + wn + ni * 16 + lrow;
    float bv = bias0[col];
    if (bias1) bv += bias1[col];
    #pragma unroll
    for (int mi = 0; mi < 4; ++mi) {
      const int row = mbase + wm + mi * 16 + rbase;
      f32x4 v = acc[mi][ni];
      C[(long)(row + 0) * N + col] = v.x + bv;
      C[(long)(row + 1) * N + col] = v.y + bv;
      C[(long)(row + 2) * N + col] = v.z + bv;
      C[(long)(row + 3) * N + col] = v.w + bv;
    }
  }
}

// ---------------- cooperative LSTM scan (v3) ----------------
// 16 blocks x 256 threads (4 waves). Block j owns units 32j..32j+31 (128 gate
// rows) for all 16 batches. Each wave holds its 32 W-rows in 128 VGPRs for the
// whole scan (loaded once). h is exchanged as f32 through a double-buffered
// global buffer + per-step agent-scope counter barrier, and consumed as a
// two-term bf16 split (hi+lo planes in swizzled LDS, 2 MFMAs per k-chunk)
// so the recurrence keeps ~16-bit mantissa precision.

__global__ __launch_bounds__(256)
void lstm_scan_coop(const float* __restrict__ xW, const u16* __restrict__ Whh16,
                    const float* __restrict__ h0, const float* __restrict__ c0,
                    unsigned* __restrict__ hbuf, unsigned* __restrict__ ctr,
                    unsigned* __restrict__ hs32) {
  __shared__ __align__(16) u16 hl_hi[B_N * H_N];   // 16 KB, swizzled
  __shared__ __align__(16) u16 hl_lo[B_N * H_N];   // 16 KB, swizzled
  __shared__ float gl[ROWS * 17];                  // padded gate exchange

  const int blk  = blockIdx.x;
  const int tid  = threadIdx.x;
  const int lane = tid & 63;
  const int wv   = tid >> 6;        // 0..3
  const int u0   = blk * UPB;
  char* hiB = (char*)hl_hi;
  char* loB = (char*)hl_lo;

  // ---- hoist W slice into registers: 2 row-tiles x 16 k-chunks x i32x4 ----
  i32x4 afr[2][16];
  {
    const char* Wb = (const char*)Whh16;
    #pragma unroll
    for (int t = 0; t < 2; ++t) {
      int r = wv * 32 + t * 16 + (lane & 15);                // local gate row
      long grow = (long)(r >> 5) * H_N + u0 + (r & 31);      // gate*512 + unit
      const char* rowp = Wb + grow * (H_N * 2) + ((lane >> 4) << 4);
      #pragma unroll
      for (int kt = 0; kt < 16; ++kt)
        afr[t][kt] = *(const i32x4*)(rowp + kt * 64);
    }
  }

  // ---- epilogue mapping: thread -> (b0, b0+8) x unit u ----
  const int u  = tid & 31;
  const int b0 = tid >> 5;          // 0..7
  float c_[2];
  c_[0] = c0[(b0)     * H_N + u0 + u];
  c_[1] = c0[(b0 + 8) * H_N + u0 + u];

  // ---- stage h^0 (split into hi/lo planes) ----
  #pragma unroll
  for (int q = 0; q < 16; ++q) {
    int pidx = q * 256 + tid;       // 4096 unit-pairs
    int b = pidx >> 8, j = pidx & 255;
    float f0 = h0[b * H_N + 2 * j], f1 = h0[b * H_N + 2 * j + 1];
    u16 h0a = f2bf(f0), h1a = f2bf(f1);
    u16 l0a = f2bf(f0 - bf2f(h0a)), l1a = f2bf(f1 - bf2f(h1a));
    unsigned wa = (unsigned)(b * 1024 + j * 4) ^ ((unsigned)(b & 7) << 4);
    *(unsigned*)(hiB + wa) = (unsigned)h0a | ((unsigned)h1a << 16);
    *(unsigned*)(loB + wa) = (unsigned)l0a | ((unsigned)l1a << 16);
  }
  __syncthreads();

  // fragment addressing (B operand = h rows by batch)
  const unsigned hrow  = (unsigned)(lane & 15);
  const unsigned hbase = hrow * 1024;
  const unsigned hswz  = (hrow & 7) << 4;
  const unsigned ksub  = ((unsigned)(lane >> 4)) << 4;

  for (int s = 0; s < S_N; ++s) {
    // xW prefetch (independent of h; hides under MFMA)
    float xw[2][4];
    #pragma unroll
    for (int p = 0; p < 2; ++p) {
      const float* xp = xW + (size_t)((b0 + p * 8) * S_N + s) * G4_N + u0 + u;
      xw[p][0] = xp[0]; xw[p][1] = xp[512]; xw[p][2] = xp[1024]; xw[p][3] = xp[1536];
    }

    // gates[128 rows][16 batches] = W_slice * (h_hi + h_lo)
    f32x4 acc0 = {0.f, 0.f, 0.f, 0.f};
    f32x4 acc1 = {0.f, 0.f, 0.f, 0.f};
    #pragma unroll
    for (int kt = 0; kt < 16; ++kt) {
      unsigned off = (hbase + (unsigned)kt * 64 + ksub) ^ hswz;
      i32x4 bhi = *(const i32x4*)(hiB + off);
      i32x4 blo = *(const i32x4*)(loB + off);
      mfma_bf16_16x16x32(acc0, afr[0][kt], bhi);
      mfma_bf16_16x16x32(acc1, afr[1][kt], bhi);
      mfma_bf16_16x16x32(acc0, afr[0][kt], blo);
      mfma_bf16_16x16x32(acc1, afr[1][kt], blo);
    }
    // MFMA->VALU/DS read hazard: inline-asm MFMA is invisible to the compiler's
    // hazard recognizer -> insert wait states manually before reading acc.
    asm volatile("s_nop 7\n\ts_nop 7\n\ts_nop 7");

    {
      int rb = wv * 32 + ((lane >> 4) << 2);
      int bc = lane & 15;
      gl[(rb + 0)  * 17 + bc] = acc0.x;
      gl[(rb + 1)  * 17 + bc] = acc0.y;
      gl[(rb + 2)  * 17 + bc] = acc0.z;
      gl[(rb + 3)  * 17 + bc] = acc0.w;
      gl[(rb + 16) * 17 + bc] = acc1.x;
      gl[(rb + 17) * 17 + bc] = acc1.y;
      gl[(rb + 18) * 17 + bc] = acc1.z;
      gl[(rb + 19) * 17 + bc] = acc1.w;
    }
    __syncthreads();

    #pragma unroll
    for (int p = 0; p < 2; ++p) {
      const int bb = b0 + p * 8;
      float gi = gl[(u)      * 17 + bb] + xw[p][0];
      float gf = gl[(32 + u) * 17 + bb] + xw[p][1];
      float gg = gl[(64 + u) * 17 + bb] + xw[p][2];
      float go = gl[(96 + u) * 17 + bb] + xw[p][3];
      gi = 1.f / (1.f + expf(-gi));
      gf = 1.f / (1.f + expf(-gf));
      gg = tanhf(gg);
      go = 1.f / (1.f + expf(-go));
      c_[p] = gf * c_[p] + gi * gg;
      float hv = go * tanhf(c_[p]);

      // output hs (bf16 pairs via lane exchange)
      unsigned hb16  = (unsigned)f2bf(hv);
      unsigned other = (unsigned)__shfl_xor((int)hb16, 1);
      if ((u & 1) == 0)
        hs32[((size_t)(bb * S_N + s) * H_N + u0 + u) >> 1] = hb16 | (other << 16);

      // exchange h (full f32) for next step
      if (s < S_N - 1)
        __hip_atomic_store(&hbuf[(s & 1) * (B_N * H_N) + bb * H_N + u0 + u],
                           __float_as_uint(hv), __ATOMIC_RELAXED, __HIP_MEMORY_SCOPE_AGENT);
    }

    if (s == S_N - 1) break;

    __syncthreads();  // all waves' h stores drained (vmcnt 0 before barrier)
    if (tid == 0) {
      __threadfence();  // flush local L2 to coherent point
      __hip_atomic_fetch_add(&ctr[s], 1u, __ATOMIC_RELEASE, __HIP_MEMORY_SCOPE_AGENT);
      while (__hip_atomic_load(&ctr[s], __ATOMIC_ACQUIRE, __HIP_MEMORY_SCOPE_AGENT) < NBLK)
        __builtin_amdgcn_s_sleep(2);
      __threadfence();  // invalidate caches before reading remote h
    }
    __syncthreads();

    // stage h^{s+1}: read f32, split to bf16 hi/lo planes (swizzled)
    const unsigned pbase = (unsigned)((s & 1) * (B_N * H_N));
    #pragma unroll
    for (int q = 0; q < 16; ++q) {
      int pidx = q * 256 + tid;
      int b = pidx >> 8, j = pidx & 255;
      unsigned w0 = __hip_atomic_load(&hbuf[pbase + b * H_N + 2 * j],
                                      __ATOMIC_RELAXED, __HIP_MEMORY_SCOPE_AGENT);
      unsigned w1 = __hip_atomic_load(&hbuf[pbase + b * H_N + 2 * j + 1],
                                      __ATOMIC_RELAXED, __HIP_MEMORY_SCOPE_AGENT);
      float f0 = __uint_as_float(w0), f1 = __uint_as_float(w1);
      u16 h0a = f2bf(f0), h1a = f2bf(f1);
      u16 l0a = f2bf(f0 - bf2f(h0a)), l1a = f2bf(f1 - bf2f(h1a));
      unsigned wa = (unsigned)(b * 1024 + j * 4) ^ ((unsigned)(b & 7) << 4);
      *(unsigned*)(hiB + wa) = (unsigned)h0a | ((unsigned)h1a << 16);
      *(unsigned*)(loB + wa) = (unsigned)l0a | ((unsigned)l1a << 16);
    }
    __syncthreads();
  }
}

// ---------------- launcher ----------------

extern "C" void kernel_launch(void* const* d_in, const int* in_sizes, int n_in,
                              void* d_out, int out_size, void* d_ws, size_t ws_size,
                              hipStream_t stream) {
  const int*   target = (const int*)  d_in[0];
  const float* h0     = (const float*)d_in[1];
  const float* c0     = (const float*)d_in[2];
  const float* emb    = (const float*)d_in[3];
  const float* W_ih   = (const float*)d_in[4];
  const float* W_hh   = (const float*)d_in[5];
  const float* b_ih   = (const float*)d_in[6];
  const float* b_hh   = (const float*)d_in[7];
  const float* out_b  = (const float*)d_in[8];
  float* out = (float*)d_out;

  char* ws = (char*)d_ws;
  u16*      E16   = (u16*)     (ws);              // V*H bf16        32,768,000 B
  u16*      Wih16 = (u16*)     (ws + 32768000);   // 4H*H bf16        2,097,152 B
  u16*      Whh16 = (u16*)     (ws + 34865152);   // 4H*H bf16        2,097,152 B
  float*    xW    = (float*)   (ws + 36962304);   // B*S*4H f32      33,554,432 B
  u16*      hs16  = (u16*)     (ws + 70516736);   // B*S*H bf16       4,194,304 B
  unsigned* hbuf  = (unsigned*)(ws + 74711040);   // 2*B*H u32           65,536 B
  unsigned* ctr   = (unsigned*)(ws + 74776576);   // 256 u32              1,024 B
  (void)ws_size; (void)in_sizes; (void)n_in; (void)out_size;

  cast_bf16_kernel<<<2048, 256, 0, stream>>>(emb,  E16,   (V_N * H_N) / 4);
  cast_bf16_kernel<<<1024, 256, 0, stream>>>(W_ih, Wih16, (G4_N * H_N) / 4);
  cast_bf16_kernel<<<1024, 256, 0, stream>>>(W_hh, Whh16, (G4_N * H_N) / 4);
  zero_ctr_kernel <<<1, 256, 0, stream>>>(ctr);

  // xW = emb[tokens] @ W_ih^T + (b_ih + b_hh)
  gemm_bf16_128<true><<<dim3(G4_N / 128, (B_N * S_N) / 128), 256, 0, stream>>>(
      E16, Wih16, xW, G4_N, b_ih, b_hh, target);

  lstm_scan_coop<<<NBLK, 256, 0, stream>>>(xW, Whh16, h0, c0, hbuf, ctr,
                                           (unsigned*)hs16);

  // logits = hs @ E^T + out_bias
  gemm_bf16_128<false><<<dim3(V_N / 128, (B_N * S_N) / 128), 256, 0, stream>>>(
      hs16, E16, out, V_N, out_b, nullptr, nullptr);
}

// Round 4
// 1261.771 us; speedup vs baseline: 6.5175x; 1.8837x over previous
//
#include <hip/hip_runtime.h>
#include <stdint.h>

#define B_N 16
#define S_N 256
#define H_N 512
#define V_N 32000
#define G4_N 2048
#define START_TOK 1
#define NBLK 16   // scan blocks
#define UPB 32    // hidden units per scan block
#define ROWS 128  // gate rows per scan block (4 * UPB)

typedef float f32x4 __attribute__((ext_vector_type(4)));
typedef int   i32x4 __attribute__((ext_vector_type(4)));
typedef unsigned short u16;
typedef u16 u16x4 __attribute__((ext_vector_type(4)));
typedef unsigned u32x2 __attribute__((ext_vector_type(2)));

static __device__ __forceinline__ u16 f2bf(float f) {
  unsigned u = __float_as_uint(f);
  return (u16)((u + 0x7fffu + ((u >> 16) & 1u)) >> 16);  // RNE
}
static __device__ __forceinline__ float bf2f(u16 b) {
  return __uint_as_float(((unsigned)b) << 16);
}

// MFMA, A-operand pinned in AGPRs (resident across the whole scan).
static __device__ __forceinline__ void mfma_av(f32x4& d, i32x4 a, i32x4 b) {
  asm("v_mfma_f32_16x16x32_bf16 %0, %1, %2, %0" : "+v"(d) : "a"(a), "v"(b));
}
static __device__ __forceinline__ void mfma_vv(f32x4& d, i32x4 a, i32x4 b) {
  asm("v_mfma_f32_16x16x32_bf16 %0, %1, %2, %0" : "+v"(d) : "v"(a), "v"(b));
}

static __device__ __forceinline__ void async16(const void* g, void* l) {
  __builtin_amdgcn_global_load_lds((const __attribute__((address_space(1))) unsigned*)g,
                                   (__attribute__((address_space(3))) unsigned*)l,
                                   16, 0, 0);
}

// LLC-direct 16B load (bypass L1+L2): cross-XCD coherent for hbuf.
static __device__ __forceinline__ f32x4 llc16(const float* p) {
  f32x4 v;
  asm volatile("global_load_dwordx4 %0, %1, off sc0 sc1" : "=v"(v) : "v"(p));
  return v;
}

// fast transcendentals (TRANS->VALU hazard covered by s_nop 1)
static __device__ __forceinline__ float vexp2(float x) {
  float r; asm("v_exp_f32 %0, %1\n\ts_nop 1" : "=v"(r) : "v"(x)); return r;
}
static __device__ __forceinline__ float vrcp(float x) {
  float r; asm("v_rcp_f32 %0, %1\n\ts_nop 1" : "=v"(r) : "v"(x)); return r;
}
static __device__ __forceinline__ float fsig(float x) {
  return vrcp(1.f + vexp2(-1.44269504f * x));
}
static __device__ __forceinline__ float ftanh(float x) {
  return 1.f - 2.f * vrcp(1.f + vexp2(2.88539008f * x));
}

// ---------------- prep kernels ----------------

__global__ void cast_bf16_kernel(const float* __restrict__ in, u16* __restrict__ out, int n4) {
  int i = blockIdx.x * blockDim.x + threadIdx.x;
  int stride = gridDim.x * blockDim.x;
  for (int q = i; q < n4; q += stride) {
    f32x4 v = *(const f32x4*)(in + 4l * q);
    u16x4 o;
    o.x = f2bf(v.x); o.y = f2bf(v.y); o.z = f2bf(v.z); o.w = f2bf(v.w);
    *(u16x4*)(out + 4l * q) = o;
  }
}

__global__ void zero_ctr_kernel(unsigned* __restrict__ ctr) {
  ctr[threadIdx.x] = 0u;
}

// ---------------- bf16 MFMA GEMM ----------------
// GATHER=false: C[M][N] = A * Bm^T + bias  (round-1 verified, unchanged)
// GATHER=true : A-rows gathered via tokens; output scattered to the scan's
//               transposed layout xWt[s][blk][g][b][u].

template<bool GATHER>
__global__ __launch_bounds__(256)
void gemm_bf16_128(const u16* __restrict__ A, const u16* __restrict__ Bm,
                   float* __restrict__ C, int N,
                   const float* __restrict__ bias0, const float* __restrict__ bias1,
                   const int* __restrict__ target) {
  constexpr int K = H_N;  // 512
  __shared__ u16 Alds[128 * 32];
  __shared__ u16 Blds[128 * 32];
  const int tid  = threadIdx.x;
  const int lane = tid & 63;
  const int wq   = tid >> 6;
  const int mbase = blockIdx.y * 128;
  const int nbase = blockIdx.x * 128;

  const int r     = tid >> 2;
  const int off16 = (tid & 3) << 4;

  long arow0, arow1;
  if (GATHER) {
    int m0 = mbase + r, m1 = mbase + 64 + r;
    int t0 = m0 & (S_N - 1), b0 = m0 >> 8;
    int t1 = m1 & (S_N - 1), b1 = m1 >> 8;
    arow0 = (t0 == 0) ? START_TOK : target[b0 * S_N + t0 - 1];
    arow1 = (t1 == 0) ? START_TOK : target[b1 * S_N + t1 - 1];
  } else {
    arow0 = mbase + r;
    arow1 = mbase + 64 + r;
  }
  const long brow0 = nbase + r, brow1 = nbase + 64 + r;

  char* AldsB = (char*)Alds;
  char* BldsB = (char*)Blds;
  const char* Ab = (const char*)A;
  const char* Bb = (const char*)Bm;
  const int ldsw = wq << 10;

  const int wm   = (wq >> 1) << 6;
  const int wn   = (wq & 1) << 6;
  const int lrow = lane & 15;
  const int lk   = (lane >> 4) << 3;

  f32x4 acc[4][4] = {};

  for (int kt = 0; kt < K / 32; ++kt) {
    __syncthreads();
    const long kb = kt * 64 + off16;
    async16(Ab + arow0 * (K * 2) + kb, AldsB + ldsw);
    async16(Ab + arow1 * (K * 2) + kb, AldsB + 4096 + ldsw);
    async16(Bb + brow0 * (K * 2) + kb, BldsB + ldsw);
    async16(Bb + brow1 * (K * 2) + kb, BldsB + 4096 + ldsw);
    __syncthreads();

    i32x4 a[4], b[4];
    #pragma unroll
    for (int mi = 0; mi < 4; ++mi)
      a[mi] = *(const i32x4*)(AldsB + (((wm + mi * 16 + lrow) << 5) + lk) * 2);
    #pragma unroll
    for (int ni = 0; ni < 4; ++ni)
      b[ni] = *(const i32x4*)(BldsB + (((wn + ni * 16 + lrow) << 5) + lk) * 2);
    #pragma unroll
    for (int mi = 0; mi < 4; ++mi)
      #pragma unroll
      for (int ni = 0; ni < 4; ++ni)
        mfma_vv(acc[mi][ni], a[mi], b[ni]);
  }
  asm volatile("s_nop 7\n\ts_nop 7");

  const int rbase = (lane >> 4) << 2;
  #pragma unroll
  for (int ni = 0; ni < 4; ++ni) {
    const int col = nbase + wn + ni * 16 + lrow;
    float bv = bias0[col];
    if (bias1) bv += bias1[col];
    #pragma unroll
    for (int mi = 0; mi < 4; ++mi) {
      const int row = mbase + wm + mi * 16 + rbase;
      f32x4 v = acc[mi][ni];
      if (GATHER) {
        // scatter to xWt[s][blk][g][b][u]; rows row..row+3 = s..s+3 (same b)
        int b  = row >> 8, s0 = row & (S_N - 1);
        int g  = col >> 9, blkc = (col >> 5) & 15, uu = col & 31;
        size_t base = (((size_t)s0 * 16 + blkc) * 4 + g) * 512 + b * 32 + uu;
        C[base]         = v.x + bv;
        C[base + 32768] = v.y + bv;
        C[base + 65536] = v.z + bv;
        C[base + 98304] = v.w + bv;
      } else {
        C[(long)(row + 0) * N + col] = v.x + bv;
        C[(long)(row + 1) * N + col] = v.y + bv;
        C[(long)(row + 2) * N + col] = v.z + bv;
        C[(long)(row + 3) * N + col] = v.w + bv;
      }
    }
  }
}

// ---------------- cooperative LSTM scan (v4) ----------------
// 16 blocks x 256 threads. Block j owns units 32j..32j+31 (128 gate rows) for
// all 16 batches. W slice pinned in AGPRs (128/wave) for the whole scan.
// h exchanged as f32 via LLC-direct (sc0 sc1) accesses, double-buffered, with
// a relaxed agent-scope counter barrier per step. NO cache-nuking fences:
// __syncthreads' vmcnt(0) drain gives release ordering; sc-flag loads give
// acquire freshness. h consumed as two-term bf16 split (hi+lo LDS planes).

__global__ __launch_bounds__(256, 1)
void lstm_scan_coop(const float* __restrict__ xWt, const u16* __restrict__ Whh16,
                    const float* __restrict__ h0, const float* __restrict__ c0,
                    unsigned* __restrict__ hbuf, unsigned* __restrict__ ctr,
                    unsigned* __restrict__ hs32) {
  __shared__ __align__(16) u16 hl_hi[B_N * H_N];   // 16 KB, swizzled
  __shared__ __align__(16) u16 hl_lo[B_N * H_N];   // 16 KB, swizzled
  __shared__ __align__(16) float glT[16 * 132];    // gate exchange [batch][row+pad]

  const int blk  = blockIdx.x;
  const int tid  = threadIdx.x;
  const int lane = tid & 63;
  const int wv   = tid >> 6;        // 0..3
  const int u0   = blk * UPB;
  char* hiB = (char*)hl_hi;
  char* loB = (char*)hl_lo;

  // ---- hoist W slice into AGPRs: 2 row-tiles x 16 k-chunks x i32x4 ----
  i32x4 afr[2][16];
  {
    const char* Wb = (const char*)Whh16;
    #pragma unroll
    for (int t = 0; t < 2; ++t) {
      int r = wv * 32 + t * 16 + (lane & 15);                // local gate row
      long grow = (long)(r >> 5) * H_N + u0 + (r & 31);      // gate*512 + unit
      const char* rowp = Wb + grow * (H_N * 2) + ((lane >> 4) << 4);
      #pragma unroll
      for (int kt = 0; kt < 16; ++kt)
        afr[t][kt] = *(const i32x4*)(rowp + kt * 64);
    }
  }

  // ---- epilogue mapping: thread -> (b0, b0+8) x unit u ----
  const int u  = tid & 31;
  const int b0 = tid >> 5;          // 0..7
  float c_[2];
  c_[0] = c0[(b0)     * H_N + u0 + u];
  c_[1] = c0[(b0 + 8) * H_N + u0 + u];

  // ---- stage h^0 (split into hi/lo planes, swizzled) ----
  #pragma unroll
  for (int q = 0; q < 8; ++q) {
    int cidx = (q * 256 + tid) * 4;   // f32 index, 4-aligned
    f32x4 v = *(const f32x4*)(h0 + cidx);
    int b = cidx >> 9, j0 = (cidx & 511) >> 1;   // j0 even
    u16 h0a = f2bf(v.x), h1a = f2bf(v.y), h2a = f2bf(v.z), h3a = f2bf(v.w);
    u32x2 hw, lw;
    hw.x = (unsigned)h0a | ((unsigned)h1a << 16);
    hw.y = (unsigned)h2a | ((unsigned)h3a << 16);
    lw.x = (unsigned)f2bf(v.x - bf2f(h0a)) | ((unsigned)f2bf(v.y - bf2f(h1a)) << 16);
    lw.y = (unsigned)f2bf(v.z - bf2f(h2a)) | ((unsigned)f2bf(v.w - bf2f(h3a)) << 16);
    unsigned wa = (unsigned)(b * 1024 + j0 * 4) ^ ((unsigned)(b & 7) << 4);
    *(u32x2*)(hiB + wa) = hw;
    *(u32x2*)(loB + wa) = lw;
  }
  __syncthreads();

  // fragment addressing (B operand = h rows by batch)
  const unsigned hrow  = (unsigned)(lane & 15);
  const unsigned hbase = hrow * 1024;
  const unsigned hswz  = (hrow & 7) << 4;
  const unsigned ksub  = ((unsigned)(lane >> 4)) << 4;

  for (int s = 0; s < S_N; ++s) {
    // xWt loads (contiguous per block; independent of h -> hides under MFMA)
    const float* xb = xWt + (size_t)s * 32768 + blk * 2048 + b0 * 32 + u;
    float x00 = xb[0],   x01 = xb[512], x02 = xb[1024], x03 = xb[1536];
    float x10 = xb[256], x11 = xb[768], x12 = xb[1280], x13 = xb[1792];

    // gates[128 rows][16 batches] = W_slice * (h_hi + h_lo), 4 indep chains
    f32x4 a00 = {0.f,0.f,0.f,0.f}, a01 = {0.f,0.f,0.f,0.f};
    f32x4 a10 = {0.f,0.f,0.f,0.f}, a11 = {0.f,0.f,0.f,0.f};
    #pragma unroll
    for (int kt = 0; kt < 16; ++kt) {
      unsigned off = (hbase + (unsigned)(kt * 64) + ksub) ^ hswz;
      i32x4 bhi = *(const i32x4*)(hiB + off);
      i32x4 blo = *(const i32x4*)(loB + off);
      mfma_av(a00, afr[0][kt], bhi);
      mfma_av(a10, afr[1][kt], bhi);
      mfma_av(a01, afr[0][kt], blo);
      mfma_av(a11, afr[1][kt], blo);
    }
    asm volatile("s_nop 7\n\ts_nop 7\n\ts_nop 7");  // MFMA->VALU hazard

    f32x4 g0 = a00 + a01;
    f32x4 g1 = a10 + a11;
    {
      int bc = lane & 15, ks = lane >> 4;
      float* p0 = glT + bc * 132 + wv * 32 + ks * 4;
      *(f32x4*)(p0)      = g0;   // rows wv*32 + ks*4 + {0..3}
      *(f32x4*)(p0 + 16) = g1;   // rows +16
    }
    __syncthreads();

    #pragma unroll
    for (int p = 0; p < 2; ++p) {
      const int bb = b0 + p * 8;
      const float* gp = glT + bb * 132 + u;
      float gi = gp[0]  + (p ? x10 : x00);
      float gf = gp[32] + (p ? x11 : x01);
      float gg = gp[64] + (p ? x12 : x02);
      float go = gp[96] + (p ? x13 : x03);
      gi = fsig(gi); gf = fsig(gf); gg = ftanh(gg); go = fsig(go);
      c_[p] = gf * c_[p] + gi * gg;
      float hv = go * ftanh(c_[p]);

      // output hs (bf16 pairs via lane exchange)
      unsigned hb16  = (unsigned)f2bf(hv);
      unsigned other = (unsigned)__shfl_xor((int)hb16, 1);
      if ((u & 1) == 0)
        hs32[((size_t)(bb * S_N + s) * H_N + u0 + u) >> 1] = hb16 | (other << 16);

      // exchange h (f32, LLC-direct) for next step
      if (s < S_N - 1)
        __hip_atomic_store(&hbuf[(s & 1) * (B_N * H_N) + bb * H_N + u0 + u],
                           __float_as_uint(hv), __ATOMIC_RELAXED, __HIP_MEMORY_SCOPE_AGENT);
    }

    if (s == S_N - 1) break;

    __syncthreads();  // vmcnt(0) drain: all h stores at LLC before ctr add
    if (tid == 0) {
      __hip_atomic_fetch_add(&ctr[s], 1u, __ATOMIC_RELAXED, __HIP_MEMORY_SCOPE_AGENT);
      while (__hip_atomic_load(&ctr[s], __ATOMIC_RELAXED, __HIP_MEMORY_SCOPE_AGENT) < NBLK)
        __builtin_amdgcn_s_sleep(1);
    }
    __syncthreads();

    // stage h^{s+1}: LLC-direct 16B loads, split to bf16 hi/lo planes
    const float* hb = (const float*)hbuf + (s & 1) * (B_N * H_N);
    f32x4 tv[8];
    #pragma unroll
    for (int q = 0; q < 8; ++q)
      tv[q] = llc16(hb + (q * 256 + tid) * 4);
    asm volatile("s_waitcnt vmcnt(0)" ::: "memory");
    __builtin_amdgcn_sched_barrier(0);   // rule #18: keep uses below the wait
    #pragma unroll
    for (int q = 0; q < 8; ++q) {
      int cidx = (q * 256 + tid) * 4;
      int b = cidx >> 9, j0 = (cidx & 511) >> 1;
      f32x4 v = tv[q];
      u16 h0a = f2bf(v.x), h1a = f2bf(v.y), h2a = f2bf(v.z), h3a = f2bf(v.w);
      u32x2 hw, lw;
      hw.x = (unsigned)h0a | ((unsigned)h1a << 16);
      hw.y = (unsigned)h2a | ((unsigned)h3a << 16);
      lw.x = (unsigned)f2bf(v.x - bf2f(h0a)) | ((unsigned)f2bf(v.y - bf2f(h1a)) << 16);
      lw.y = (unsigned)f2bf(v.z - bf2f(h2a)) | ((unsigned)f2bf(v.w - bf2f(h3a)) << 16);
      unsigned wa = (unsigned)(b * 1024 + j0 * 4) ^ ((unsigned)(b & 7) << 4);
      *(u32x2*)(hiB + wa) = hw;
      *(u32x2*)(loB + wa) = lw;
    }
    __syncthreads();
  }
}

// ---------------- launcher ----------------

extern "C" void kernel_launch(void* const* d_in, const int* in_sizes, int n_in,
                              void* d_out, int out_size, void* d_ws, size_t ws_size,
                              hipStream_t stream) {
  const int*   target = (const int*)  d_in[0];
  const float* h0     = (const float*)d_in[1];
  const float* c0     = (const float*)d_in[2];
  const float* emb    = (const float*)d_in[3];
  const float* W_ih   = (const float*)d_in[4];
  const float* W_hh   = (const float*)d_in[5];
  const float* b_ih   = (const float*)d_in[6];
  const float* b_hh   = (const float*)d_in[7];
  const float* out_b  = (const float*)d_in[8];
  float* out = (float*)d_out;

  char* ws = (char*)d_ws;
  u16*      E16   = (u16*)     (ws);              // V*H bf16        32,768,000 B
  u16*      Wih16 = (u16*)     (ws + 32768000);   // 4H*H bf16        2,097,152 B
  u16*      Whh16 = (u16*)     (ws + 34865152);   // 4H*H bf16        2,097,152 B
  float*    xWt   = (float*)   (ws + 36962304);   // B*S*4H f32      33,554,432 B
  u16*      hs16  = (u16*)     (ws + 70516736);   // B*S*H bf16       4,194,304 B
  unsigned* hbuf  = (unsigned*)(ws + 74711040);   // 2*B*H u32           65,536 B
  unsigned* ctr   = (unsigned*)(ws + 74776576);   // 256 u32              1,024 B
  (void)ws_size; (void)in_sizes; (void)n_in; (void)out_size;

  cast_bf16_kernel<<<2048, 256, 0, stream>>>(emb,  E16,   (V_N * H_N) / 4);
  cast_bf16_kernel<<<1024, 256, 0, stream>>>(W_ih, Wih16, (G4_N * H_N) / 4);
  cast_bf16_kernel<<<1024, 256, 0, stream>>>(W_hh, Whh16, (G4_N * H_N) / 4);
  zero_ctr_kernel <<<1, 256, 0, stream>>>(ctr);

  // xWt[s][blk][g][b][u] = (emb[tokens] @ W_ih^T + b_ih + b_hh), transposed
  gemm_bf16_128<true><<<dim3(G4_N / 128, (B_N * S_N) / 128), 256, 0, stream>>>(
      E16, Wih16, xWt, G4_N, b_ih, b_hh, target);

  lstm_scan_coop<<<NBLK, 256, 0, stream>>>(xWt, Whh16, h0, c0, hbuf, ctr,
                                           (unsigned*)hs16);

  // logits = hs @ E^T + out_bias
  gemm_bf16_128<false><<<dim3(V_N / 128, (B_N * S_N) / 128), 256, 0, stream>>>(
      hs16, E16, out, V_N, out_b, nullptr, nullptr);
}

// Round 7
// 1214.108 us; speedup vs baseline: 6.7734x; 1.0393x over previous
//
#include <hip/hip_runtime.h>
#include <stdint.h>

#define B_N 16
#define S_N 256
#define H_N 512
#define V_N 32000
#define G4_N 2048
#define START_TOK 1
#define NBLK 16   // scan blocks (4 waves each, 64 wave-slots total)

typedef float f32x4 __attribute__((ext_vector_type(4)));
typedef int   i32x4 __attribute__((ext_vector_type(4)));
typedef unsigned short u16;
typedef u16 u16x4 __attribute__((ext_vector_type(4)));

static __device__ __forceinline__ u16 f2bf(float f) {
  unsigned u = __float_as_uint(f);
  return (u16)((u + 0x7fffu + ((u >> 16) & 1u)) >> 16);  // RNE
}
static __device__ __forceinline__ float bf2f(u16 b) {
  return __uint_as_float(((unsigned)b) << 16);
}

// MFMA: A pinned in AGPRs, B/acc in VGPRs (gfx950 unified file).
static __device__ __forceinline__ void mfma_av(f32x4& d, i32x4 a, i32x4 b) {
  asm("v_mfma_f32_16x16x32_bf16 %0, %1, %2, %0" : "+v"(d) : "a"(a), "v"(b));
}
static __device__ __forceinline__ void mfma_vv(f32x4& d, i32x4 a, i32x4 b) {
  asm("v_mfma_f32_16x16x32_bf16 %0, %1, %2, %0" : "+v"(d) : "v"(a), "v"(b));
}

static __device__ __forceinline__ void async16(const void* g, void* l) {
  __builtin_amdgcn_global_load_lds((const __attribute__((address_space(1))) unsigned*)g,
                                   (__attribute__((address_space(3))) unsigned*)l,
                                   16, 0, 0);
}

// LLC-direct (cross-XCD coherent) 16B load (r4-proven primitive).
static __device__ __forceinline__ i32x4 llc16(const void* p) {
  i32x4 v;
  asm volatile("global_load_dwordx4 %0, %1, off sc0 sc1" : "=v"(v) : "v"(p));
  return v;
}

// fast transcendentals (TRANS->VALU hazard covered by s_nop 1)
static __device__ __forceinline__ float vexp2(float x) {
  float r; asm("v_exp_f32 %0, %1\n\ts_nop 1" : "=v"(r) : "v"(x)); return r;
}
static __device__ __forceinline__ float vrcp(float x) {
  float r; asm("v_rcp_f32 %0, %1\n\ts_nop 1" : "=v"(r) : "v"(x)); return r;
}
static __device__ __forceinline__ float fsig(float x) {
  return vrcp(1.f + vexp2(-1.44269504f * x));
}
static __device__ __forceinline__ float ftanh(float x) {
  return 1.f - 2.f * vrcp(1.f + vexp2(2.88539008f * x));
}

// ---------------- prep kernels ----------------

__global__ void cast_bf16_kernel(const float* __restrict__ in, u16* __restrict__ out, int n4) {
  int i = blockIdx.x * blockDim.x + threadIdx.x;
  int stride = gridDim.x * blockDim.x;
  for (int q = i; q < n4; q += stride) {
    f32x4 v = *(const f32x4*)(in + 4l * q);
    u16x4 o;
    o.x = f2bf(v.x); o.y = f2bf(v.y); o.z = f2bf(v.z); o.w = f2bf(v.w);
    *(u16x4*)(out + 4l * q) = o;
  }
}

// zero ctr + stage h0 into plane slot 0 (packed hi/lo bf16 unit-pairs).
// 16 blocks x 256 = 4096 threads, one unit-pair each.
__global__ void init_scan_kernel(const float* __restrict__ h0, unsigned* __restrict__ Phi,
                                 unsigned* __restrict__ Plo, unsigned* __restrict__ ctr) {
  int i = blockIdx.x * blockDim.x + threadIdx.x;   // 0..4095
  if (i < 256) ctr[i] = 0u;
  float f0 = h0[2 * i];
  float f1 = h0[2 * i + 1];
  u16 h0a = f2bf(f0), h1a = f2bf(f1);
  u16 l0a = f2bf(f0 - bf2f(h0a)), l1a = f2bf(f1 - bf2f(h1a));
  Phi[i] = (unsigned)h0a | ((unsigned)h1a << 16);
  Plo[i] = (unsigned)l0a | ((unsigned)l1a << 16);
}

// ---------------- bf16 MFMA GEMM ----------------
// GATHER=false: C[M][N] = A * Bm^T + bias  (round-1 verified)
// GATHER=true : A-rows gathered via tokens; output scattered to the scan's
//               layout xWt[s][wid][b][ul][g] (wid = unit>>3, ul = unit&7).

template<bool GATHER>
__global__ __launch_bounds__(256)
void gemm_bf16_128(const u16* __restrict__ A, const u16* __restrict__ Bm,
                   float* __restrict__ C, int N,
                   const float* __restrict__ bias0, const float* __restrict__ bias1,
                   const int* __restrict__ target) {
  constexpr int K = H_N;  // 512
  __shared__ u16 Alds[128 * 32];
  __shared__ u16 Blds[128 * 32];
  const int tid  = threadIdx.x;
  const int lane = tid & 63;
  const int wq   = tid >> 6;
  const int mbase = blockIdx.y * 128;
  const int nbase = blockIdx.x * 128;

  const int r     = tid >> 2;
  const int off16 = (tid & 3) << 4;

  long arow0, arow1;
  if (GATHER) {
    int m0 = mbase + r, m1 = mbase + 64 + r;
    int t0 = m0 & (S_N - 1), b0 = m0 >> 8;
    int t1 = m1 & (S_N - 1), b1 = m1 >> 8;
    arow0 = (t0 == 0) ? START_TOK : target[b0 * S_N + t0 - 1];
    arow1 = (t1 == 0) ? START_TOK : target[b1 * S_N + t1 - 1];
  } else {
    arow0 = mbase + r;
    arow1 = mbase + 64 + r;
  }
  const long brow0 = nbase + r, brow1 = nbase + 64 + r;

  char* AldsB = (char*)Alds;
  char* BldsB = (char*)Blds;
  const char* Ab = (const char*)A;
  const char* Bb = (const char*)Bm;
  const int ldsw = wq << 10;

  const int wm   = (wq >> 1) << 6;
  const int wn   = (wq & 1) << 6;
  const int lrow = lane & 15;
  const int lk   = (lane >> 4) << 3;

  f32x4 acc[4][4] = {};

  for (int kt = 0; kt < K / 32; ++kt) {
    __syncthreads();
    const long kb = kt * 64 + off16;
    async16(Ab + arow0 * (K * 2) + kb, AldsB + ldsw);
    async16(Ab + arow1 * (K * 2) + kb, AldsB + 4096 + ldsw);
    async16(Bb + brow0 * (K * 2) + kb, BldsB + ldsw);
    async16(Bb + brow1 * (K * 2) + kb, BldsB + 4096 + ldsw);
    __syncthreads();

    i32x4 a[4], b[4];
    #pragma unroll
    for (int mi = 0; mi < 4; ++mi)
      a[mi] = *(const i32x4*)(AldsB + (((wm + mi * 16 + lrow) << 5) + lk) * 2);
    #pragma unroll
    for (int ni = 0; ni < 4; ++ni)
      b[ni] = *(const i32x4*)(BldsB + (((wn + ni * 16 + lrow) << 5) + lk) * 2);
    #pragma unroll
    for (int mi = 0; mi < 4; ++mi)
      #pragma unroll
      for (int ni = 0; ni < 4; ++ni)
        mfma_vv(acc[mi][ni], a[mi], b[ni]);
  }
  asm volatile("s_nop 7\n\ts_nop 7");

  const int rbase = (lane >> 4) << 2;
  #pragma unroll
  for (int ni = 0; ni < 4; ++ni) {
    const int col = nbase + wn + ni * 16 + lrow;
    float bv = bias0[col];
    if (bias1) bv += bias1[col];
    #pragma unroll
    for (int mi = 0; mi < 4; ++mi) {
      const int row = mbase + wm + mi * 16 + rbase;
      f32x4 v = acc[mi][ni];
      if (GATHER) {
        int b  = row >> 8, s0 = row & (S_N - 1);
        int ug = col & 511, g = col >> 9;
        size_t base = (((size_t)s0 * 64 + (ug >> 3)) * 16 + b) * 32 + (ug & 7) * 4 + g;
        C[base]         = v.x + bv;   // s0
        C[base + 32768] = v.y + bv;   // s0+1
        C[base + 65536] = v.z + bv;
        C[base + 98304] = v.w + bv;
      } else {
        C[(long)(row + 0) * N + col] = v.x + bv;
        C[(long)(row + 1) * N + col] = v.y + bv;
        C[(long)(row + 2) * N + col] = v.z + bv;
        C[(long)(row + 3) * N + col] = v.w + bv;
      }
    }
  }
}

// ---------------- cooperative LSTM scan (v7) ----------------
// r4's PROVEN sync skeleton (stores -> __syncthreads vmcnt-drain -> tid0 RMW
// ctr[s] + poll + __syncthreads -> stage -> __syncthreads), with v6's compute:
// A-rows remapped (row = unit_local*4 + gate) so each lane's 4 accumulators
// are {i,f,g,o} for one (unit,batch) -> activations lane-local, no glT LDS
// exchange. h exchanged as packed-u32 bf16 hi/lo unit-pairs (Phi/Plo, double
// buffered); consumer staging is a pure copy into swizzled LDS planes.

__global__ __launch_bounds__(256, 1)
void lstm_scan_coop(const float* __restrict__ xWt, const u16* __restrict__ Whh16,
                    const float* __restrict__ c0, unsigned* __restrict__ Phi,
                    unsigned* __restrict__ Plo, unsigned* __restrict__ ctr,
                    unsigned* __restrict__ hs32) {
  __shared__ __align__(16) u16 hl_hi[B_N * H_N];   // 16 KB, swizzled
  __shared__ __align__(16) u16 hl_lo[B_N * H_N];   // 16 KB, swizzled

  const int blk  = blockIdx.x;
  const int tid  = threadIdx.x;
  const int lane = tid & 63;
  const int wv   = tid >> 6;            // 0..3
  const int wid  = blk * 4 + wv;        // 0..63 (global wave id = unit group)
  const int fr   = lane & 15;
  const int ksub = lane >> 4;           // 0..3
  const int b    = fr;                  // batch (B-operand column)
  char* hiB = (char*)hl_hi;
  char* loB = (char*)hl_lo;

  // ---- A fragments (W slice) into AGPRs, resident across all 256 steps ----
  // A-row ar <-> gate (ar&3), unit wid*8 + t*4 + (ar>>2)
  i32x4 afr[2][16];
  {
    const char* Wb = (const char*)Whh16;
    #pragma unroll
    for (int t = 0; t < 2; ++t) {
      long grow = (long)(fr & 3) * H_N + wid * 8 + t * 4 + (fr >> 2);
      const char* rowp = Wb + grow * (H_N * 2) + ksub * 16;
      #pragma unroll
      for (int kt = 0; kt < 16; ++kt)
        afr[t][kt] = *(const i32x4*)(rowp + kt * 64);
    }
  }

  // lane-local cell state for units ua = wid*8+ksub, ub = ua+4
  const int ua = wid * 8 + ksub;
  const int ub = ua + 4;
  float ca = c0[b * H_N + ua];
  float cb = c0[b * H_N + ub];

  const bool stlane = ((ksub & 1) == 0);       // lanes that emit packed stores
  const int  pua    = wid * 4 + (ksub >> 1);   // unit-pair index for (ua,ua+1)

  // ---- stage h^0 planes from global slot 0 (init-written) ----
  {
    i32x4 th[4], tl[4];
    #pragma unroll
    for (int q = 0; q < 4; ++q) {
      int cidx = (q * 256 + tid) * 4;
      th[q] = llc16(Phi + cidx);
      tl[q] = llc16(Plo + cidx);
    }
    asm volatile("s_waitcnt vmcnt(0)" ::: "memory");
    __builtin_amdgcn_sched_barrier(0);
    #pragma unroll
    for (int q = 0; q < 4; ++q) {
      int cidx = (q * 256 + tid) * 4;
      int bb = cidx >> 8, j = cidx & 255;
      unsigned wa = (unsigned)(bb * 1024 + j * 4) ^ ((unsigned)(bb & 7) << 4);
      *(i32x4*)(hiB + wa) = th[q];
      *(i32x4*)(loB + wa) = tl[q];
    }
  }
  __syncthreads();

  // B-fragment addressing (r4-proven swizzled layout)
  const unsigned hbase = (unsigned)(fr * 1024);
  const unsigned hswz  = ((unsigned)(fr & 7)) << 4;
  const unsigned k16   = ((unsigned)ksub) << 4;

  for (int s = 0; s < S_N; ++s) {
    // xW for this step (plain cached loads, contiguous per wave)
    const float* xp = xWt + ((size_t)s * 64 + wid) * 512 + b * 32;
    f32x4 xwa = *(const f32x4*)(xp + ksub * 4);
    f32x4 xwb = *(const f32x4*)(xp + 16 + ksub * 4);

    // gates = W_slice * (h_hi + h_lo), 4 independent MFMA chains
    f32x4 a00 = {0.f,0.f,0.f,0.f}, a01 = {0.f,0.f,0.f,0.f};
    f32x4 a10 = {0.f,0.f,0.f,0.f}, a11 = {0.f,0.f,0.f,0.f};
    #pragma unroll
    for (int kt = 0; kt < 16; ++kt) {
      unsigned off = (hbase + (unsigned)(kt * 64) + k16) ^ hswz;
      i32x4 bhi = *(const i32x4*)(hiB + off);
      i32x4 blo = *(const i32x4*)(loB + off);
      mfma_av(a00, afr[0][kt], bhi);
      mfma_av(a10, afr[1][kt], bhi);
      mfma_av(a01, afr[0][kt], blo);
      mfma_av(a11, afr[1][kt], blo);
    }
    asm volatile("s_nop 7\n\ts_nop 7\n\ts_nop 7");  // MFMA->VALU hazard

    f32x4 ga = a00 + a01;   // {i,f,g,o} for (ua, b)
    f32x4 gb = a10 + a11;   // {i,f,g,o} for (ub, b)

    float gia = fsig(ga.x + xwa.x), gfa = fsig(ga.y + xwa.y);
    float gga = ftanh(ga.z + xwa.z), goa = fsig(ga.w + xwa.w);
    ca = gfa * ca + gia * gga;
    float ha = goa * ftanh(ca);

    float gib = fsig(gb.x + xwb.x), gfb = fsig(gb.y + xwb.y);
    float ggb = ftanh(gb.z + xwb.z), gob = fsig(gb.w + xwb.w);
    cb = gfb * cb + gib * ggb;
    float hb = gob * ftanh(cb);

    u16 ha16 = f2bf(ha), hb16 = f2bf(hb);
    u16 la16 = f2bf(ha - bf2f(ha16));
    u16 lb16 = f2bf(hb - bf2f(hb16));

    // pack unit-pairs: even-ksub lane holds unit u, partner (lane^16) u+1
    unsigned pha = (unsigned)ha16 | ((unsigned)__shfl_xor((int)(unsigned)ha16, 16) << 16);
    unsigned phb = (unsigned)hb16 | ((unsigned)__shfl_xor((int)(unsigned)hb16, 16) << 16);
    unsigned pla = (unsigned)la16 | ((unsigned)__shfl_xor((int)(unsigned)la16, 16) << 16);
    unsigned plb = (unsigned)lb16 | ((unsigned)__shfl_xor((int)(unsigned)lb16, 16) << 16);

    if (stlane) {
      // hs output [b][s][u] as u32 pairs (plain cached stores)
      hs32[((size_t)b * S_N + s) * (H_N / 2) + pua]     = pha;
      hs32[((size_t)b * S_N + s) * (H_N / 2) + pua + 2] = phb;
      if (s < S_N - 1) {
        const size_t pb = ((size_t)((s + 1) & 1) * B_N + b) * (H_N / 2);
        __hip_atomic_store(&Phi[pb + pua],     pha, __ATOMIC_RELAXED, __HIP_MEMORY_SCOPE_AGENT);
        __hip_atomic_store(&Phi[pb + pua + 2], phb, __ATOMIC_RELAXED, __HIP_MEMORY_SCOPE_AGENT);
        __hip_atomic_store(&Plo[pb + pua],     pla, __ATOMIC_RELAXED, __HIP_MEMORY_SCOPE_AGENT);
        __hip_atomic_store(&Plo[pb + pua + 2], plb, __ATOMIC_RELAXED, __HIP_MEMORY_SCOPE_AGENT);
      }
    }

    if (s == S_N - 1) break;

    __syncthreads();  // compiler emits s_waitcnt vmcnt(0) before s_barrier
    if (tid == 0) {
      __hip_atomic_fetch_add(&ctr[s], 1u, __ATOMIC_RELAXED, __HIP_MEMORY_SCOPE_AGENT);
      while (__hip_atomic_load(&ctr[s], __ATOMIC_RELAXED, __HIP_MEMORY_SCOPE_AGENT) < NBLK)
        __builtin_amdgcn_s_sleep(1);
    }
    __syncthreads();

    // stage h^{s+1} planes: LLC-direct copy into swizzled LDS (no split math)
    {
      const unsigned slotoff = (unsigned)(((s + 1) & 1) * 4096);
      i32x4 th[4], tl[4];
      #pragma unroll
      for (int q = 0; q < 4; ++q) {
        int cidx = (q * 256 + tid) * 4;
        th[q] = llc16(Phi + slotoff + cidx);
        tl[q] = llc16(Plo + slotoff + cidx);
      }
      asm volatile("s_waitcnt vmcnt(0)" ::: "memory");
      __builtin_amdgcn_sched_barrier(0);
      #pragma unroll
      for (int q = 0; q < 4; ++q) {
        int cidx = (q * 256 + tid) * 4;
        int bb = cidx >> 8, j = cidx & 255;
        unsigned wa = (unsigned)(bb * 1024 + j * 4) ^ ((unsigned)(bb & 7) << 4);
        *(i32x4*)(hiB + wa) = th[q];
        *(i32x4*)(loB + wa) = tl[q];
      }
    }
    __syncthreads();
  }
}

// ---------------- launcher ----------------

extern "C" void kernel_launch(void* const* d_in, const int* in_sizes, int n_in,
                              void* d_out, int out_size, void* d_ws, size_t ws_size,
                              hipStream_t stream) {
  const int*   target = (const int*)  d_in[0];
  const float* h0     = (const float*)d_in[1];
  const float* c0     = (const float*)d_in[2];
  const float* emb    = (const float*)d_in[3];
  const float* W_ih   = (const float*)d_in[4];
  const float* W_hh   = (const float*)d_in[5];
  const float* b_ih   = (const float*)d_in[6];
  const float* b_hh   = (const float*)d_in[7];
  const float* out_b  = (const float*)d_in[8];
  float* out = (float*)d_out;

  char* ws = (char*)d_ws;
  u16*      E16   = (u16*)     (ws);              // V*H bf16        32,768,000 B
  u16*      Wih16 = (u16*)     (ws + 32768000);   // 4H*H bf16        2,097,152 B
  u16*      Whh16 = (u16*)     (ws + 34865152);   // 4H*H bf16        2,097,152 B
  float*    xWt   = (float*)   (ws + 36962304);   // B*S*4H f32      33,554,432 B
  u16*      hs16  = (u16*)     (ws + 70516736);   // B*S*H bf16       4,194,304 B
  unsigned* Phi   = (unsigned*)(ws + 74711040);   // 2*B*H/2 u32         32,768 B
  unsigned* Plo   = (unsigned*)(ws + 74743808);   // 2*B*H/2 u32         32,768 B
  unsigned* ctr   = (unsigned*)(ws + 74776576);   // 256 u32              1,024 B
  (void)ws_size; (void)in_sizes; (void)n_in; (void)out_size;

  cast_bf16_kernel<<<2048, 256, 0, stream>>>(emb,  E16,   (V_N * H_N) / 4);
  cast_bf16_kernel<<<1024, 256, 0, stream>>>(W_ih, Wih16, (G4_N * H_N) / 4);
  cast_bf16_kernel<<<1024, 256, 0, stream>>>(W_hh, Whh16, (G4_N * H_N) / 4);
  init_scan_kernel<<<16, 256, 0, stream>>>(h0, Phi, Plo, ctr);

  // xWt[s][wid][b][ul][g] = (emb[tokens] @ W_ih^T + b_ih + b_hh), scattered
  gemm_bf16_128<true><<<dim3(G4_N / 128, (B_N * S_N) / 128), 256, 0, stream>>>(
      E16, Wih16, xWt, G4_N, b_ih, b_hh, target);

  lstm_scan_coop<<<NBLK, 256, 0, stream>>>(xWt, Whh16, c0, Phi, Plo, ctr,
                                           (unsigned*)hs16);

  // logits = hs @ E^T + out_bias
  gemm_bf16_128<false><<<dim3(V_N / 128, (B_N * S_N) / 128), 256, 0, stream>>>(
      hs16, E16, out, V_N, out_b, nullptr, nullptr);
}